// Round 13
// baseline (196.635 us; speedup 1.0000x reference)
//
#include <hip/hip_runtime.h>
#include <math.h>

typedef __attribute__((ext_vector_type(4))) float floatx4;
typedef __attribute__((ext_vector_type(8))) short shortx8;   // 8 bf16
typedef __attribute__((ext_vector_type(4))) short shortx4;   // 4 bf16 (8B)

#define NB 4
#define CC 768
#define WW 2048
#define HH 12
#define DD 64
#define GG 4
#define CG 192
#define HPG 3
#define L2E 1.4426950408889634f
#define C18 0.18033688011112043f   // 0.125 * log2(e)
#define MSH 11.541560327111707f    // 8.0 * log2(e)  (fixed softmax shift)
#define WSZ (GG * CG * CG)         // 147456

__device__ __forceinline__ float fast_exp2(float x) {
    return __builtin_amdgcn_exp2f(x);   // v_exp_f32 (log2 domain)
}

__device__ __forceinline__ short f2bf(float f) {
    union { float f; unsigned u; } v; v.f = f;
    unsigned r = v.u + 0x7fffu + ((v.u >> 16) & 1u);   // RNE
    return (short)(r >> 16);
}

// pack two floats -> packed bf16 pair (RNE), single instr where available
__device__ __forceinline__ unsigned pack_bf16(float a, float b) {
#if __has_builtin(__builtin_amdgcn_cvt_pk_bf16_f32)
    typedef __bf16 bf16x2_t __attribute__((ext_vector_type(2)));
    bf16x2_t p = __builtin_amdgcn_cvt_pk_bf16_f32(a, b);
    return __builtin_bit_cast(unsigned, p);
#else
    union { float f; unsigned u; } x, y; x.f = a; y.f = b;
    unsigned ra = (x.u + 0x7fffu + ((x.u >> 16) & 1u)) >> 16;
    unsigned rb = (y.u + 0x7fffu + ((y.u >> 16) & 1u)) & 0xffff0000u;
    return ra | rb;
#endif
}

struct __align__(8) u2 { unsigned x, y; };

// async global->LDS, 16B per lane; lds base must be wave-uniform
__device__ __forceinline__ void gl_lds16(const void* g, void* l) {
    __builtin_amdgcn_global_load_lds(
        (const __attribute__((address_space(1))) unsigned int*)g,
        (__attribute__((address_space(3))) unsigned int*)l, 16, 0, 0);
}

// ---------------------------------------------------------------------------
// Prep (merged): blocks [0,1536): x -> XTh [N,W,C] bf16 (LDS-transposed,
// coalesced both ways). blocks [1536,2112): weights -> Wf fragment-major.
// ---------------------------------------------------------------------------
__global__ __launch_bounds__(256) void prep(
    const float* __restrict__ x,
    const float* __restrict__ wq, const float* __restrict__ wk,
    const float* __restrict__ wv,
    short* __restrict__ XTh, short* __restrict__ Wf)
{
    __shared__ short Th[64 * 72];
    const int tid = threadIdx.x;
    const int b   = blockIdx.x;

    if (b < 1536) {
        const int w0 = (b & 31) * 64;
        const int c0 = ((b >> 5) % 12) * 64;
        const int n  = b / 384;
        const int w  = tid & 63;
        const int cb = (tid >> 6) * 16;

        float xv[16];
        #pragma unroll
        for (int j = 0; j < 16; ++j)
            xv[j] = x[((size_t)n * CC + c0 + cb + j) * WW + w0 + w];

        shortx8 hi0, hi1;
        #pragma unroll
        for (int j = 0; j < 8; ++j) { hi0[j] = f2bf(xv[j]); hi1[j] = f2bf(xv[j + 8]); }
        *(shortx8*)&Th[w * 72 + cb]     = hi0;
        *(shortx8*)&Th[w * 72 + cb + 8] = hi1;
        __syncthreads();

        const int wr = tid >> 2;
        const int cc = (tid & 3) * 16;
        const size_t ro = ((size_t)n * WW + w0 + wr) * CC + c0 + cc;
        *(shortx8*)&XTh[ro]     = *(const shortx8*)&Th[wr * 72 + cc];
        *(shortx8*)&XTh[ro + 8] = *(const shortx8*)&Th[wr * 72 + cc + 8];
    } else {
        const int t = (b - 1536) * 256 + tid;          // < WSZ
        const int g  = t / (CG * CG);
        const int r  = t - g * (CG * CG);
        const int o  = r / CG;
        const int k  = r - o * CG;
        const int off = (((g * 12 + (o >> 4)) * 6 + (k >> 5)) * 512)
                      + ((k >> 3) & 3) * 128 + (o & 15) * 8 + (k & 7);
        const float* src[3] = {wq, wk, wv};
        #pragma unroll
        for (int m = 0; m < 3; ++m)
            Wf[m * WSZ + off] = f2bf(src[m][t]);
    }
}

// ---------------------------------------------------------------------------
// Grouped 1x1 conv as single-bf16 MFMA GEMM (unchanged from R11/R12).
// grid: 1536 1-D blocks, block 256.
// ---------------------------------------------------------------------------
__global__ __launch_bounds__(256) void qkv_gemm(
    const short* __restrict__ XTh, const short* __restrict__ Wf,
    const float* __restrict__ bq, const float* __restrict__ bk,
    const float* __restrict__ bv,
    short* __restrict__ Qb, short* __restrict__ Kb, short* __restrict__ Vb)
{
    __shared__ __align__(16) char smem[26112];
    short* Xh_l = (short*)smem;              // 24576 B, [p][24 chunks] swz

    const int lin  = blockIdx.x;
    const int xcd  = lin & 7;
    const int iw   = lin >> 3;              // 0..191
    const int mat  = iw % 3;
    const int tile = (iw / 3) * 8 + xcd;    // 0..511
    const int p0   = (tile & 31) * 64;
    const int g    = (tile >> 5) & 3;
    const int n    = tile >> 7;

    const int tid  = threadIdx.x;
    const int wid  = __builtin_amdgcn_readfirstlane(tid >> 6);
    const int lane = tid & 63;
    const int l15  = lane & 15;
    const int quad = lane >> 4;
    const int ob   = wid * 48;

    {
        const short* xhb = XTh + ((size_t)n * WW + p0) * CC + g * CG;
        #pragma unroll
        for (int rd = 0; rd < 6; ++rd) {
            const int Lb = rd * 256 + wid * 64;           // wave-uniform
            const int L  = Lb + lane;
            const int p  = (L * 2731) >> 16;              // L / 24
            const int sc = L - p * 24;
            const int ss = (sc & ~7) | ((sc & 7) ^ (p & 7));
            gl_lds16(xhb + (size_t)p * CC + ss * 8, &Xh_l[Lb * 8]);
        }
    }
    __syncthreads();

    floatx4 acc[3][4];
    #pragma unroll
    for (int mi = 0; mi < 3; ++mi)
        #pragma unroll
        for (int ni = 0; ni < 4; ++ni) acc[mi][ni] = (floatx4)0.0f;

    const short* wfm = Wf + (size_t)mat * WSZ + lane * 8;

    #pragma unroll
    for (int ks = 0; ks < 6; ++ks) {
        shortx8 ah[3], bh[4];
        #pragma unroll
        for (int mi = 0; mi < 3; ++mi)
            ah[mi] = *(const shortx8*)(wfm + (((g * 12 + wid * 3 + mi) * 6 + ks) << 9));
        #pragma unroll
        for (int ni = 0; ni < 4; ++ni) {
            const int p  = ni * 16 + l15;
            const int vp = (ks >> 1) * 8 + ((((ks & 1) * 4) + quad) ^ (p & 7));
            bh[ni] = *(const shortx8*)&Xh_l[(p * 24 + vp) * 8];
        }
        #pragma unroll
        for (int mi = 0; mi < 3; ++mi)
            #pragma unroll
            for (int ni = 0; ni < 4; ++ni)
                acc[mi][ni] = __builtin_amdgcn_mfma_f32_16x16x32_bf16(ah[mi], bh[ni], acc[mi][ni], 0, 0, 0);
    }

    const float* bias = (mat == 0) ? bq : (mat == 1) ? bk : bv;
    short* Y = (mat == 0) ? Qb : (mat == 1) ? Kb : Vb;

    __syncthreads();   // all frag reads of Xh_l done before overlay

    if (mat < 2) {
        short* T = (short*)smem;   // 64*200*2 = 25600 B
        #pragma unroll
        for (int mi = 0; mi < 3; ++mi) {
            float4 b4 = *(const float4*)&bias[g * CG + ob + mi * 16 + quad * 4];
            const int o = ob + mi * 16 + quad * 4;
            #pragma unroll
            for (int ni = 0; ni < 4; ++ni) {
                const int p = ni * 16 + l15;
                T[p * 200 + o]     = f2bf(acc[mi][ni][0] + b4.x);
                T[p * 200 + o + 1] = f2bf(acc[mi][ni][1] + b4.y);
                T[p * 200 + o + 2] = f2bf(acc[mi][ni][2] + b4.z);
                T[p * 200 + o + 3] = f2bf(acc[mi][ni][3] + b4.w);
            }
        }
        __syncthreads();
        #pragma unroll
        for (int hc = 0; hc < HPG; ++hc) {
            const size_t nh = (size_t)n * HH + g * HPG + hc;
            #pragma unroll
            for (int half = 0; half < 2; ++half) {
                const int idx = tid + half * 256;
                const int p  = idx >> 3;
                const int dc = (idx & 7) * 8;
                *(shortx8*)&Y[(nh * WW + p0 + p) * DD + dc] =
                    *(const shortx8*)&T[p * 200 + hc * 64 + dc];
            }
        }
    } else {
        short* T = (short*)smem;   // 192*68*2 = 26112 B
        #pragma unroll
        for (int mi = 0; mi < 3; ++mi) {
            float4 b4 = *(const float4*)&bias[g * CG + ob + mi * 16 + quad * 4];
            const int o = ob + mi * 16 + quad * 4;
            #pragma unroll
            for (int ni = 0; ni < 4; ++ni) {
                const int p = ni * 16 + l15;
                T[(o)     * 68 + p] = f2bf(acc[mi][ni][0] + b4.x);
                T[(o + 1) * 68 + p] = f2bf(acc[mi][ni][1] + b4.y);
                T[(o + 2) * 68 + p] = f2bf(acc[mi][ni][2] + b4.z);
                T[(o + 3) * 68 + p] = f2bf(acc[mi][ni][3] + b4.w);
            }
        }
        __syncthreads();
        #pragma unroll
        for (int pass = 0; pass < 6; ++pass) {
            const int idx = tid + pass * 256;
            const int o  = idx >> 3;
            const int pc = (idx & 7) * 8;
            const size_t nh = (size_t)n * HH + g * HPG + (o >> 6);
            const int d = o & 63;
            *(shortx8*)&Y[(nh * DD + d) * WW + p0 + pc] =
                *(const shortx8*)&T[o * 68 + pc];
        }
    }
}

// ---------------------------------------------------------------------------
// Attention v3: S computed TRANSPOSED (A=K, B=Q) so each lane's P values are
// key-contiguous: packed cvt + 4x ds_write_b64 replace 16 scattered b16
// writes + 64 VALU rounding ops. PV = mfma(A=V^T, B=P) yields O^T[d][q] =
// output layout. Double-buffered LDS staging (R12), one barrier/tile.
// grid: 1536 1-D blocks (XCD swizzle), block 256. LDS 50176 B.
// ---------------------------------------------------------------------------
#define PST 72
#define RST 68

__global__ __launch_bounds__(256) void attn_split(
    const short* __restrict__ Qb, const short* __restrict__ Kb,
    const short* __restrict__ Vb, const float* __restrict__ mask,
    float* __restrict__ out)
{
    __shared__ __align__(16) char smem[50176];
    // [0]:Ks0 8K [8192]:Ks1 8K [16384]:Vs0 8K [24576]:Vs1 8K
    // [32768]: Pl 9216  [41984]: Ml 8192
    short* Pl = (short*)(smem + 32768);
    float* Ml = (float*)(smem + 41984);

    const int lin  = blockIdx.x;
    const int xcd  = lin & 7;
    const int slot = lin >> 3;               // 0..191
    const int pair = xcd * 6 + (slot >> 5);  // 0..47
    const int qt   = slot & 31;
    const int n    = pair / HH;
    const int h    = pair % HH;
    const int q0   = qt * 64;

    const int tid  = threadIdx.x;
    const int wid  = __builtin_amdgcn_readfirstlane(tid >> 6);
    const int lane = tid & 63;
    const int l15  = lane & 15;
    const int quad = lane >> 4;

    const size_t nh = (size_t)n * HH + h;
    const short* Kbase = Kb + nh * WW * DD;   // [key][d]
    const short* Vbase = Vb + nh * DD * WW;   // [d][w]

    // stage pre-transformed mask once
    {
        const float* mbase = mask + (size_t)n * WW;
        #pragma unroll
        for (int i = 0; i < WW / 256; ++i)
            Ml[tid + i * 256] = fmaf(mbase[tid + i * 256], L2E, -MSH);
    }

    shortx8 qf[2];
    {
        const short* qp = Qb + (nh * WW + q0 + wid * 16 + l15) * DD + quad * 8;
        qf[0] = *(const shortx8*)(qp);
        qf[1] = *(const shortx8*)(qp + 32);
    }

    floatx4 oacc[4];
    #pragma unroll
    for (int nn2 = 0; nn2 < 4; ++nn2) oacc[nn2] = (floatx4)0.0f;
    float lsumA = 0.f, lsumB = 0.f;   // per-lane l partial for q = l15

    short* Pw = Pl + wid * 16 * PST;

    // hoisted staging addresses (per lane, advance per tile)
    const int r0  = wid * 16 + (lane >> 3);
    const int r1  = r0 + 8;
    const int cg0 = (lane & 7) ^ (r0 & 7);
    const int cg1 = (lane & 7) ^ (r1 & 7);
    const short* kp0 = Kbase + (size_t)r0 * DD + cg0 * 8;
    const short* kp1 = Kbase + (size_t)r1 * DD + cg1 * 8;
    const short* vp0 = Vbase + (size_t)r0 * WW + cg0 * 8;
    const short* vp1 = Vbase + (size_t)r1 * WW + cg1 * 8;
    const int KR0 = (wid * 16) * 64, KR1 = (wid * 16 + 8) * 64;   // LDS offs

    #define STAGE(j, bb)                                                      \
        do {                                                                  \
            short* ksd = (short*)(smem + (bb) * 8192);                        \
            short* vsd = (short*)(smem + 16384 + (bb) * 8192);                \
            gl_lds16(kp0 + (size_t)(j) * 64 * DD, ksd + KR0);                 \
            gl_lds16(kp1 + (size_t)(j) * 64 * DD, ksd + KR1);                 \
            gl_lds16(vp0 + (j) * 64, vsd + KR0);                              \
            gl_lds16(vp1 + (j) * 64, vsd + KR1);                              \
        } while (0)

    STAGE(0, 0);
    __syncthreads();   // tile 0 ready (also covers Ml)

    for (int kt = 0; kt < WW / 64; ++kt) {
        const int bb = kt & 1;
        if (kt + 1 < WW / 64) STAGE(kt + 1, 1 - bb);

        const short* Ks_l = (const short*)(smem + bb * 8192);
        const short* Vs_l = (const short*)(smem + 16384 + bb * 8192);
        const int k0 = kt * 64;

        shortx8 kf[4][2], vf[4][2];
        #pragma unroll
        for (int jj = 0; jj < 4; ++jj) {
            const int r = 16 * jj + l15;
            #pragma unroll
            for (int hf = 0; hf < 2; ++hf)
                kf[jj][hf] = *(const shortx8*)&Ks_l[r * 64 + (((hf * 4 + quad) ^ (r & 7)) * 8)];
        }
        #pragma unroll
        for (int nn2 = 0; nn2 < 4; ++nn2) {
            const int r = 16 * nn2 + l15;
            #pragma unroll
            for (int hf = 0; hf < 2; ++hf)
                vf[nn2][hf] = *(const shortx8*)&Vs_l[r * 64 + (((hf * 4 + quad) ^ (r & 7)) * 8)];
        }

        // ---- S^T = K Q^T : lane holds S[q=l15][key=k0+16jj+quad*4+r] ----
        floatx4 sacc[4];
        #pragma unroll
        for (int jj = 0; jj < 4; ++jj) {
            sacc[jj] = (floatx4)0.0f;
            sacc[jj] = __builtin_amdgcn_mfma_f32_16x16x32_bf16(kf[jj][0], qf[0], sacc[jj], 0, 0, 0);
            sacc[jj] = __builtin_amdgcn_mfma_f32_16x16x32_bf16(kf[jj][1], qf[1], sacc[jj], 0, 0, 0);
        }

        // ---- P = exp2(S*C18 + mask'), packed pairs, key-contiguous writes --
        #pragma unroll
        for (int jj = 0; jj < 4; ++jj) {
            float4 mvv = *(const float4*)&Ml[k0 + 16 * jj + quad * 4];
            float p0 = fast_exp2(fmaf(sacc[jj][0], C18, mvv.x));
            float p1 = fast_exp2(fmaf(sacc[jj][1], C18, mvv.y));
            float p2 = fast_exp2(fmaf(sacc[jj][2], C18, mvv.z));
            float p3 = fast_exp2(fmaf(sacc[jj][3], C18, mvv.w));
            lsumA += p0 + p1;
            lsumB += p2 + p3;
            u2 pk = { pack_bf16(p0, p1), pack_bf16(p2, p3) };
            *(u2*)&Pw[l15 * PST + 16 * jj + quad * 4] = pk;
        }

        // P as B-frag for PV: B[k=key][n=q], lane n=l15, contiguous keys
        shortx8 pf0 = *(const shortx8*)&Pw[l15 * PST + quad * 8];
        shortx8 pf1 = *(const shortx8*)&Pw[l15 * PST + 32 + quad * 8];

        // ---- O^T += V^T P : C[m=d][n=q] ----
        #pragma unroll
        for (int nn2 = 0; nn2 < 4; ++nn2) {
            oacc[nn2] = __builtin_amdgcn_mfma_f32_16x16x32_bf16(vf[nn2][0], pf0, oacc[nn2], 0, 0, 0);
            oacc[nn2] = __builtin_amdgcn_mfma_f32_16x16x32_bf16(vf[nn2][1], pf1, oacc[nn2], 0, 0, 0);
        }
        __syncthreads();   // drains next-tile loads + protects bb for reuse
    }
    #undef STAGE

    // ---- l: reduce across the 4 quads holding q=l15 ----
    float lsum = lsumA + lsumB;
    lsum += __shfl_xor(lsum, 16);
    lsum += __shfl_xor(lsum, 32);
    const float linv = 1.0f / lsum;

    // ---- epilogue: O^T already [d][q]; normalize, stage, coalesced store --
    float* Ol = (float*)smem;   // 64*RST*4 = 17408 B (overlays dead buffers)
    #pragma unroll
    for (int nn2 = 0; nn2 < 4; ++nn2)
        #pragma unroll
        for (int r = 0; r < 4; ++r)
            Ol[(nn2 * 16 + quad * 4 + r) * RST + wid * 16 + l15] = oacc[nn2][r] * linv;
    __syncthreads();

    float* obase = out + (nh * DD) * WW + q0;
    #pragma unroll
    for (int it = 0; it < 4; ++it) {
        const int idx = tid + it * 256;        // 64 d x 16 q-groups
        const int q4 = (idx & 15) * 4;
        const int d  = idx >> 4;
        *(floatx4*)&obase[(size_t)d * WW + q4] = *(const floatx4*)&Ol[d * RST + q4];
    }
}

// ---------------------------------------------------------------------------
extern "C" void kernel_launch(void* const* d_in, const int* in_sizes, int n_in,
                              void* d_out, int out_size, void* d_ws, size_t ws_size,
                              hipStream_t stream) {
    const float* x    = (const float*)d_in[0];
    const float* mask = (const float*)d_in[1];
    const float* wq   = (const float*)d_in[2];
    const float* bq   = (const float*)d_in[3];
    const float* wk   = (const float*)d_in[4];
    const float* bk   = (const float*)d_in[5];
    const float* wv   = (const float*)d_in[6];
    const float* bv   = (const float*)d_in[7];
    float* out = (float*)d_out;

    const size_t per = (size_t)NB * HH * WW * DD;   // 6,291,456
    short* Qb  = (short*)d_ws;
    short* Kb  = Qb + per;
    short* Vb  = Kb + per;
    short* XTh = Vb + per;
    short* Wfp = XTh + per;                          // 3*WSZ shorts

    hipLaunchKernelGGL(prep, dim3(1536 + WSZ / 256), dim3(256), 0, stream,
                       x, wq, wk, wv, XTh, Wfp);
    hipLaunchKernelGGL(qkv_gemm, dim3(1536), dim3(256), 0, stream,
                       XTh, Wfp, bq, bk, bv, Qb, Kb, Vb);
    hipLaunchKernelGGL(attn_split, dim3(1536), dim3(256), 0, stream,
                       Qb, Kb, Vb, mask, out);
}